// Round 6
// baseline (264.298 us; speedup 1.0000x reference)
//
#include <hip/hip_runtime.h>
#include <hip/hip_bf16.h>
#include <stdint.h>

// B=2, N=128, D=512, LAYERS=3.
// Algebraic reduction: the [B,N,N,*] concat-GEMMs decompose into rank terms.
// Only rel@Wgr_c (x2) + rel3@W_esa are big MFMA GEMMs; rel1 = tanh(A[i]+C[j])
// is materialized once.  Softmax over axis i without the max pass (|s|<=~23).
// Round-6 delta vs round-5 (261.9 us): both GEMM kernels move to the
// "minimum 2-phase" schedule -- explicit LDS double-buffer, counted
// s_waitcnt vmcnt(8) + raw s_barrier (never vmcnt(0) in the loop), so the
// next tile's 8 global_load_lds stay in flight across the barrier.  The old
// __syncthreads() drained vmcnt(0) every K-step = serial L2 round trip per
// 16-32KB tile (the documented barrier-drain stall, amplified by K=8 steps).
// XCD swizzle on big GEMMs kept from round 5 (-7.6 us verified).

#define DEV static __device__ __forceinline__

typedef float  f32x4   __attribute__((ext_vector_type(4)));
typedef float  f32x16  __attribute__((ext_vector_type(16)));
typedef __bf16 bf16x8  __attribute__((ext_vector_type(8)));
typedef __bf16 bf16x4  __attribute__((ext_vector_type(4)));

DEV float tanh_fast(float x) {
  float e = __expf(2.0f * x);
  return 1.0f - 2.0f * __frcp_rn(e + 1.0f);
}

DEV void gl_lds16(const void* g, void* l) {
  __builtin_amdgcn_global_load_lds(
      (const __attribute__((address_space(1))) unsigned int*)g,
      (__attribute__((address_space(3))) unsigned int*)l, 16, 0, 0);
}

// ------------- prep: weight transpose->bf16 hi/lo, x0 split, dvec ---------------
struct WC { const float* W; __bf16* Wh; __bf16* Wl; };
struct Prep {
  WC w[7];
  const float* x0; __bf16* x0h; __bf16* x0l;
  const float* b_rel; const float* Wgrc; const float* b_gr; float* dvec;
};

__global__ __launch_bounds__(256) void prep_kernel(Prep pp) {
  const int y = blockIdx.y;
  if (y < 7) {
    const WC wc = pp.w[y];
    __shared__ float tile[32][33];
    int t = threadIdx.x;
    int tx = t & 31, ty = t >> 5;                     // 32 x 8
    int bx = blockIdx.x & 15, by = blockIdx.x >> 4;   // 16 x 16 tiles of 32x32
    int k0 = by * 32, n0 = bx * 32;
#pragma unroll
    for (int r = 0; r < 4; ++r) {
      int k = ty + r * 8;
      tile[k][tx] = wc.W[(size_t)(k0 + k) * 512 + n0 + tx];
    }
    __syncthreads();
#pragma unroll
    for (int r = 0; r < 4; ++r) {
      int n = ty + r * 8;
      float v = tile[tx][n];
      __bf16 h = (__bf16)v;
      wc.Wh[(size_t)(n0 + n) * 512 + k0 + tx] = h;
      wc.Wl[(size_t)(n0 + n) * 512 + k0 + tx] = (__bf16)(v - (float)h);
    }
  } else if (y == 7) {
    int i = blockIdx.x * 256 + threadIdx.x;
    if (i < 32768) {
      float4 v = ((const float4*)pp.x0)[i];
      float vv[4] = {v.x, v.y, v.z, v.w};
      bf16x4 h, l;
#pragma unroll
      for (int e = 0; e < 4; ++e) {
        __bf16 he = (__bf16)vv[e];
        h[e] = he;
        l[e] = (__bf16)(vv[e] - (float)he);
      }
      ((bf16x4*)pp.x0h)[i] = h;
      ((bf16x4*)pp.x0l)[i] = l;
    }
  } else {
    if (blockIdx.x < 2) {
      int n = blockIdx.x * 256 + threadIdx.x;
      float acc = pp.b_gr[n];
#pragma unroll 8
      for (int k = 0; k < 512; ++k) acc += pp.b_rel[k] * pp.Wgrc[(size_t)k * 512 + n];
      pp.dvec[n] = acc;
    }
  }
}

// ------------- small MFMA GEMM batch: out = act(X@W + bias + add) ---------------
// M=256, N=512, K=512. 64x64 tiles, split-precision compensated bf16.
// All 13 ops in the pipeline pass Xl/Wl, so the compensated path is
// hard-coded (keeps the per-wave load count exactly 8 for vmcnt math).
struct MOp {
  const __bf16* Xh; const __bf16* Xl;   // [256,512]
  const __bf16* Wh; const __bf16* Wl;   // [512(n),512(k)] transposed
  const float* bias;                    // [512] or null
  const float* add;                     // [256,512] or null
  float* outf;                          // [256,512] or null
  __bf16* outh; __bf16* outl;           // [256,512] or null
  int act;                              // 1 = tanh
};
struct MBatch { MOp op[5]; };

__global__ __launch_bounds__(256, 2) void mfma_small_kernel(MBatch batch) {
  const MOp o = batch.op[blockIdx.y];
  const int m0 = ((int)blockIdx.x >> 3) * 64;
  const int n0 = ((int)blockIdx.x & 7) * 64;
  __shared__ __bf16 Ah[2][64 * 64], Al[2][64 * 64], Bh[2][64 * 64], Bl[2][64 * 64];
  const int t = threadIdx.x, lane = t & 63, wave = t >> 6;
  const int waveM = wave >> 1, waveN = wave & 1;
  const int lr = lane >> 3, lc = (lane & 7) * 8;

  // 8 gl_lds16 per wave per call (vmcnt counting depends on this)
  auto stage = [&](int k0, int sel) {
#pragma unroll
    for (int r = 0; r < 2; ++r) {
      const int rb = r * 32 + wave * 8;
      gl_lds16(o.Xh + (size_t)(m0 + rb + lr) * 512 + k0 + lc, &Ah[sel][rb * 64]);
      gl_lds16(o.Wh + (size_t)(n0 + rb + lr) * 512 + k0 + lc, &Bh[sel][rb * 64]);
      gl_lds16(o.Xl + (size_t)(m0 + rb + lr) * 512 + k0 + lc, &Al[sel][rb * 64]);
      gl_lds16(o.Wl + (size_t)(n0 + rb + lr) * 512 + k0 + lc, &Bl[sel][rb * 64]);
    }
  };

  f32x4 vzero = {0.f, 0.f, 0.f, 0.f};
  f32x4 acc[2][2];
#pragma unroll
  for (int a = 0; a < 2; ++a)
#pragma unroll
    for (int c = 0; c < 2; ++c) acc[a][c] = vzero;

  stage(0, 0);
#pragma unroll 1
  for (int kt = 0; kt < 8; ++kt) {
    const int sel = kt & 1;
    if (kt < 7) {
      stage((kt + 1) * 64, sel ^ 1);
      asm volatile("s_waitcnt vmcnt(8)" ::: "memory");  // tile kt drained; kt+1 in flight
    } else {
      asm volatile("s_waitcnt vmcnt(0)" ::: "memory");
    }
    __builtin_amdgcn_s_barrier();
    __builtin_amdgcn_sched_barrier(0);
#pragma unroll
    for (int kk = 0; kk < 2; ++kk) {
      const int koff = kk * 32 + (lane >> 4) * 8;
      const int ml = lane & 15;
      bf16x8 ah[2], bh[2], al[2], bl[2];
#pragma unroll
      for (int tm = 0; tm < 2; ++tm)
        ah[tm] = *(const bf16x8*)&Ah[sel][(waveM * 32 + tm * 16 + ml) * 64 + koff];
#pragma unroll
      for (int tn = 0; tn < 2; ++tn)
        bh[tn] = *(const bf16x8*)&Bh[sel][(waveN * 32 + tn * 16 + ml) * 64 + koff];
#pragma unroll
      for (int tm = 0; tm < 2; ++tm)
        al[tm] = *(const bf16x8*)&Al[sel][(waveM * 32 + tm * 16 + ml) * 64 + koff];
#pragma unroll
      for (int tn = 0; tn < 2; ++tn)
        bl[tn] = *(const bf16x8*)&Bl[sel][(waveN * 32 + tn * 16 + ml) * 64 + koff];
#pragma unroll
      for (int tm = 0; tm < 2; ++tm)
#pragma unroll
        for (int tn = 0; tn < 2; ++tn) {
          acc[tm][tn] = __builtin_amdgcn_mfma_f32_16x16x32_bf16(ah[tm], bh[tn], acc[tm][tn], 0, 0, 0);
          acc[tm][tn] = __builtin_amdgcn_mfma_f32_16x16x32_bf16(ah[tm], bl[tn], acc[tm][tn], 0, 0, 0);
          acc[tm][tn] = __builtin_amdgcn_mfma_f32_16x16x32_bf16(al[tm], bh[tn], acc[tm][tn], 0, 0, 0);
        }
    }
    __builtin_amdgcn_s_barrier();  // reads of buf[sel] done before restage
  }

  const int quad = lane >> 4, cl = lane & 15;
#pragma unroll
  for (int tm = 0; tm < 2; ++tm) {
#pragma unroll
    for (int r = 0; r < 4; ++r) {
      const int row = m0 + waveM * 32 + tm * 16 + quad * 4 + r;
#pragma unroll
      for (int tn = 0; tn < 2; ++tn) {
        const int col = n0 + waveN * 32 + tn * 16 + cl;
        float v = acc[tm][tn][r];
        if (o.bias) v += o.bias[col];
        if (o.add) v += o.add[(size_t)row * 512 + col];
        if (o.act) v = tanh_fast(v);
        if (o.outf) o.outf[(size_t)row * 512 + col] = v;
        if (o.outh) {
          __bf16 h = (__bf16)v;
          o.outh[(size_t)row * 512 + col] = h;
          o.outl[(size_t)row * 512 + col] = (__bf16)(v - (float)h);
        }
      }
    }
  }
}

// ------------- rel1 materialization: R1[b,i,j,:] = tanh(A[b,i,:] + C[b,j,:]) ----
__global__ __launch_bounds__(256) void rel1_kernel(
    const float* __restrict__ A, const float* __restrict__ C,
    __bf16* __restrict__ R1) {
  size_t e = ((size_t)blockIdx.x * 256 + threadIdx.x) * 8;  // 8192 blocks
  int d = (int)(e & 511);
  int j = (int)((e >> 9) & 127);
  int bi = (int)(e >> 16);         // b*128 + i
  int b = bi >> 7;
  const float* ap = &A[(size_t)bi * 512 + d];
  const float* cp = &C[((size_t)(b * 128 + j)) * 512 + d];
  float av[8], cv[8];
  *(float4*)&av[0] = *(const float4*)ap;
  *(float4*)&av[4] = *(const float4*)(ap + 4);
  *(float4*)&cv[0] = *(const float4*)cp;
  *(float4*)&cv[4] = *(const float4*)(cp + 4);
  bf16x8 o;
#pragma unroll
  for (int k = 0; k < 8; ++k) o[k] = (__bf16)tanh_fast(av[k] + cv[k]);
  *(bf16x8*)&R1[e] = o;
}

// ------------- big MFMA GEMM: [32768,512] @ Wt^T, K=512, 32x32x16 --------------
// MODE 1: out bf16 tanh(acc + P[i] + Q[j]);  MODE 2: out f32 (acc + bias)
// 2-phase: LDS double-buffer, counted vmcnt(8), raw barriers.
// XCD swizzle: grid 1024 (%8==0) -> blk=(d%8)*128+d/8.
constexpr int BM = 128, BN = 128, BK = 64;
DEV int lds_off(int row) { return row * 64 + (row >> 3) * 8; }

template <int MODE>
__global__ __launch_bounds__(256, 2) void big_gemm_kernel(
    const __bf16* __restrict__ Ab, const __bf16* __restrict__ Wt,
    const float* __restrict__ P, const float* __restrict__ Q,
    const float* __restrict__ bias, __bf16* __restrict__ outb,
    float* __restrict__ outf) {
  __shared__ __bf16 As[2][BM * BK + 16 * 8];
  __shared__ __bf16 Bs[2][BN * BK + 16 * 8];
  const int t = threadIdx.x;
  const int lane = t & 63;
  const int wave = t >> 6;
  const int blk = ((int)blockIdx.x & 7) * 128 + ((int)blockIdx.x >> 3);
  const int bm = blk >> 2;                      // (b*128 + i)
  const int n0 = (blk & 3) * BN;
  const size_t r0 = (size_t)bm * BM;
  const int b = bm >> 7;
  const int i = bm & 127;
  const int waveM = wave >> 1, waveN = wave & 1;

  // 8 gl_lds16 per wave per call
  auto stage = [&](int k0, int sel) {
#pragma unroll
    for (int p2 = 0; p2 < 4; ++p2) {
      int rowg = wave * 32 + p2 * 8;
      const __bf16* ga = Ab + (r0 + rowg + (lane >> 3)) * 512 + k0 + (lane & 7) * 8;
      gl_lds16(ga, &As[sel][lds_off(rowg)]);
      const __bf16* gb = Wt + (size_t)(n0 + rowg + (lane >> 3)) * 512 + k0 + (lane & 7) * 8;
      gl_lds16(gb, &Bs[sel][lds_off(rowg)]);
    }
  };

  f32x16 acc[2][2];
#pragma unroll
  for (int a = 0; a < 2; ++a)
#pragma unroll
    for (int c = 0; c < 2; ++c) acc[a][c] = (f32x16)0.f;

  stage(0, 0);
#pragma unroll 1
  for (int kt = 0; kt < 8; ++kt) {
    const int sel = kt & 1;
    if (kt < 7) {
      stage((kt + 1) * BK, sel ^ 1);
      asm volatile("s_waitcnt vmcnt(8)" ::: "memory");
    } else {
      asm volatile("s_waitcnt vmcnt(0)" ::: "memory");
    }
    __builtin_amdgcn_s_barrier();
    __builtin_amdgcn_sched_barrier(0);
    const int ml = lane & 31;
    const int kl = (lane >> 5) * 8;
#pragma unroll
    for (int ks = 0; ks < 4; ++ks) {
      const int koff = ks * 16 + kl;
      bf16x8 af[2], bfr[2];
#pragma unroll
      for (int tm = 0; tm < 2; ++tm)
        af[tm] = *(const bf16x8*)&As[sel][lds_off(waveM * 64 + tm * 32 + ml) + koff];
#pragma unroll
      for (int tn = 0; tn < 2; ++tn)
        bfr[tn] = *(const bf16x8*)&Bs[sel][lds_off(waveN * 64 + tn * 32 + ml) + koff];
#pragma unroll
      for (int tm = 0; tm < 2; ++tm)
#pragma unroll
        for (int tn = 0; tn < 2; ++tn)
          acc[tm][tn] = __builtin_amdgcn_mfma_f32_32x32x16_bf16(af[tm], bfr[tn], acc[tm][tn], 0, 0, 0);
    }
    __builtin_amdgcn_s_barrier();  // reads of buf[sel] done before restage
  }

  const int cl = lane & 31, lg = lane >> 5;
#pragma unroll
  for (int tm = 0; tm < 2; ++tm) {
#pragma unroll
    for (int tn = 0; tn < 2; ++tn) {
      const int col = n0 + waveN * 64 + tn * 32 + cl;
      float pv;
      if (MODE == 2) pv = bias[col];
      else pv = P[((size_t)(b * 128 + i)) * 512 + col];
#pragma unroll
      for (int reg = 0; reg < 16; ++reg) {
        const int row = waveM * 64 + tm * 32 + (reg & 3) + 8 * (reg >> 2) + 4 * lg;  // j
        float v = acc[tm][tn][reg] + pv;
        if (MODE == 2) {
          outf[(r0 + row) * 512 + col] = v;
        } else {
          v += Q[((size_t)(b * 128 + row)) * 512 + col];
          outb[(r0 + row) * 512 + col] = (__bf16)tanh_fast(v);
        }
      }
    }
  }
}

// ------------- softmax over axis i (no max pass: |s| bounded), then sum over j --
__global__ __launch_bounds__(256) void softmax_l_kernel(
    const float* __restrict__ S, float* __restrict__ Lb) {
  int idx = blockIdx.x * 256 + threadIdx.x;   // = (b*128 + j)*512 + d
  int d = idx & 511;
  int j = (idx >> 9) & 127;
  int b = idx >> 16;
  const float* p = S + ((size_t)b * 16384 + j) * 512 + d;  // i = 0
  float l = 0.f;
#pragma unroll 8
  for (int ii = 0; ii < 128; ++ii) l += __expf(p[(size_t)ii * 65536]);
  Lb[idx] = __frcp_rn(l);
}

__global__ __launch_bounds__(256) void softmax_out_kernel(
    const float* __restrict__ S, const float* __restrict__ Lb,
    float* __restrict__ outp) {
  int idx = blockIdx.x * 256 + threadIdx.x;   // = (b*128 + i)*512 + d
  int d = idx & 511;
  int i = (idx >> 9) & 127;
  int b = idx >> 16;
  const float* sp = S + ((size_t)(b * 128 + i)) * 65536 + d;  // j = 0
  const float* lp = Lb + (size_t)b * 65536 + d;
  float acc = 0.f;
#pragma unroll 8
  for (int jj = 0; jj < 128; ++jj) {
    float s = sp[(size_t)jj * 512];
    acc += __expf(s) * lp[(size_t)jj * 512] * s;
  }
  outp[idx] = acc;
}

// --------------------------------------------------------------------------------
extern "C" void kernel_launch(void* const* d_in, const int* in_sizes, int n_in,
                              void* d_out, int out_size, void* d_ws, size_t ws_size,
                              hipStream_t stream) {
  const float* x0    = (const float*)d_in[0];
  const float* W_rel = (const float*)d_in[1];
  const float* b_rel = (const float*)d_in[2];
  const float* W_go  = (const float*)d_in[3];
  const float* b_go  = (const float*)d_in[4];
  const float* W_gr  = (const float*)d_in[5];
  const float* b_gr  = (const float*)d_in[6];
  const float* W_esa = (const float*)d_in[7];
  const float* b_esa = (const float*)d_in[8];

  const float* Wrel_top = W_rel;
  const float* Wrel_bot = W_rel + 512 * 512;
  const float* Wgr_a = W_gr;
  const float* Wgr_b = W_gr + 512 * 512;
  const float* Wgr_c = W_gr + 2 * 512 * 512;

  char* ws = (char*)d_ws;
  size_t off = 0;
  auto alloc = [&](size_t bytes) -> void* {
    void* p = ws + off;
    off += (bytes + 255) & ~(size_t)255;
    return p;
  };
  const size_t NREL = 16777216ull;  // B*N*N*D
  float*  S  = (float*)alloc(NREL * 4);        // 64 MB
  __bf16* R1 = (__bf16*)alloc(NREL * 2);       // 32 MB
  __bf16* R2 = (__bf16*)alloc(NREL * 2);       // 32 MB
  float* p0t  = (float*)alloc(131072 * 4);
  float* q0t  = (float*)alloc(131072 * 4);
  float* Abuf = (float*)alloc(131072 * 4);
  float* Cbuf = (float*)alloc(131072 * 4);
  float* p1   = (float*)alloc(131072 * 4);
  float* q1   = (float*)alloc(131072 * 4);
  float* p2   = (float*)alloc(131072 * 4);
  float* q2   = (float*)alloc(131072 * 4);
  float* dvec = (float*)alloc(512 * 4);
  float* Lb   = (float*)alloc(131072 * 4);
  __bf16* x0h = (__bf16*)alloc(131072 * 2);
  __bf16* x0l = (__bf16*)alloc(131072 * 2);
  __bf16* x1h = (__bf16*)alloc(131072 * 2);
  __bf16* x1l = (__bf16*)alloc(131072 * 2);
  __bf16* x2h = (__bf16*)alloc(131072 * 2);
  __bf16* x2l = (__bf16*)alloc(131072 * 2);
  __bf16* u0h = (__bf16*)alloc(131072 * 2);
  __bf16* u0l = (__bf16*)alloc(131072 * 2);
  __bf16* v0h = (__bf16*)alloc(131072 * 2);
  __bf16* v0l = (__bf16*)alloc(131072 * 2);
  __bf16* Wgo_h = (__bf16*)alloc(262144 * 2);
  __bf16* Wgo_l = (__bf16*)alloc(262144 * 2);
  __bf16* Wrt_h = (__bf16*)alloc(262144 * 2);
  __bf16* Wrt_l = (__bf16*)alloc(262144 * 2);
  __bf16* Wrb_h = (__bf16*)alloc(262144 * 2);
  __bf16* Wrb_l = (__bf16*)alloc(262144 * 2);
  __bf16* Wga_h = (__bf16*)alloc(262144 * 2);
  __bf16* Wga_l = (__bf16*)alloc(262144 * 2);
  __bf16* Wgb_h = (__bf16*)alloc(262144 * 2);
  __bf16* Wgb_l = (__bf16*)alloc(262144 * 2);
  __bf16* Wgc_h = (__bf16*)alloc(262144 * 2);
  __bf16* Wgc_l = (__bf16*)alloc(262144 * 2);
  __bf16* Wes_h = (__bf16*)alloc(262144 * 2);
  __bf16* Wes_l = (__bf16*)alloc(262144 * 2);

  float* x3out  = (float*)d_out;             // output 0
  float* relout = (float*)d_out + 131072;    // output 1

  Prep pp;
  pp.w[0] = {W_go, Wgo_h, Wgo_l};
  pp.w[1] = {Wrel_top, Wrt_h, Wrt_l};
  pp.w[2] = {Wrel_bot, Wrb_h, Wrb_l};
  pp.w[3] = {Wgr_a, Wga_h, Wga_l};
  pp.w[4] = {Wgr_b, Wgb_h, Wgb_l};
  pp.w[5] = {Wgr_c, Wgc_h, Wgc_l};
  pp.w[6] = {W_esa, Wes_h, Wes_l};
  pp.x0 = x0; pp.x0h = x0h; pp.x0l = x0l;
  pp.b_rel = b_rel; pp.Wgrc = Wgr_c; pp.b_gr = b_gr; pp.dvec = dvec;
  prep_kernel<<<dim3(256, 9), 256, 0, stream>>>(pp);

  MBatch m1 = {};
  m1.op[0] = {x0h, x0l, Wgo_h, Wgo_l, b_go, nullptr, nullptr, x1h, x1l, 1};
  m1.op[1] = {x0h, x0l, Wrt_h, Wrt_l, nullptr, nullptr, nullptr, u0h, u0l, 0};
  m1.op[2] = {x0h, x0l, Wrb_h, Wrb_l, nullptr, nullptr, nullptr, v0h, v0l, 0};
  m1.op[3] = {x0h, x0l, Wga_h, Wga_l, nullptr, nullptr, p0t, nullptr, nullptr, 0};
  m1.op[4] = {x0h, x0l, Wgb_h, Wgb_l, nullptr, nullptr, q0t, nullptr, nullptr, 0};
  mfma_small_kernel<<<dim3(32, 5), 256, 0, stream>>>(m1);

  MBatch m2 = {};
  m2.op[0] = {x1h, x1l, Wgo_h, Wgo_l, b_go, nullptr, nullptr, x2h, x2l, 1};
  m2.op[1] = {u0h, u0l, Wgc_h, Wgc_l, dvec, p0t, Abuf, nullptr, nullptr, 0};
  m2.op[2] = {v0h, v0l, Wgc_h, Wgc_l, nullptr, q0t, Cbuf, nullptr, nullptr, 0};
  m2.op[3] = {x1h, x1l, Wga_h, Wga_l, b_gr, nullptr, p1, nullptr, nullptr, 0};
  m2.op[4] = {x1h, x1l, Wgb_h, Wgb_l, nullptr, nullptr, q1, nullptr, nullptr, 0};
  mfma_small_kernel<<<dim3(32, 5), 256, 0, stream>>>(m2);

  MBatch m3 = {};
  m3.op[0] = {x2h, x2l, Wgo_h, Wgo_l, b_go, nullptr, x3out, nullptr, nullptr, 1};
  m3.op[1] = {x2h, x2l, Wga_h, Wga_l, b_gr, nullptr, p2, nullptr, nullptr, 0};
  m3.op[2] = {x2h, x2l, Wgb_h, Wgb_l, nullptr, nullptr, q2, nullptr, nullptr, 0};
  mfma_small_kernel<<<dim3(32, 3), 256, 0, stream>>>(m3);

  // rel1 = tanh(A[i] + C[j]) materialized as bf16
  rel1_kernel<<<8192, 256, 0, stream>>>(Abuf, Cbuf, R1);

  // rel2 = tanh(rel1@Wgr_c + p1[i] + q1[j])
  big_gemm_kernel<1><<<1024, 256, 0, stream>>>(R1, Wgc_h, p1, q1, nullptr, R2, nullptr);
  // rel3 = tanh(rel2@Wgr_c + p2[i] + q2[j])
  big_gemm_kernel<1><<<1024, 256, 0, stream>>>(R2, Wgc_h, p2, q2, nullptr, R1, nullptr);
  // S = rel3@W_esa + b_esa
  big_gemm_kernel<2><<<1024, 256, 0, stream>>>(R1, Wes_h, nullptr, nullptr, b_esa, nullptr, S);

  softmax_l_kernel<<<512, 256, 0, stream>>>(S, Lb);
  softmax_out_kernel<<<512, 256, 0, stream>>>(S, Lb, relout);
}

// Round 8
// 263.239 us; speedup vs baseline: 1.0040x; 1.0040x over previous
//
#include <hip/hip_runtime.h>
#include <hip/hip_bf16.h>
#include <stdint.h>

// B=2, N=128, D=512, LAYERS=3.
// Algebraic reduction: the [B,N,N,*] concat-GEMMs decompose into rank terms.
// Only rel@Wgr_c (x2) + rel3@W_esa are big MFMA GEMMs; rel1 = tanh(A[i]+C[j]).
// Softmax over axis i without the max pass (|s|<=~23 << f32 exp overflow).
// Round-8 = round-5 anchor (261.9us: XCD swizzle on big GEMMs) + rel1 folded
// into the m3 small-batch dispatch as an extra blockIdx.y slice: m3's GEMM ops
// use only 96/256 CUs (latency-bound), so rel1's 32MB write runs on the idle
// CUs -- one launch + one serialization boundary removed, hot loops untouched.
// (Round-6 counted-vmcnt: neutral, reverted.  Round-7 cooperative grid.sync:
// raced under graph capture, abandoned.)

#define DEV static __device__ __forceinline__

typedef float  f32x4   __attribute__((ext_vector_type(4)));
typedef float  f32x16  __attribute__((ext_vector_type(16)));
typedef __bf16 bf16x8  __attribute__((ext_vector_type(8)));
typedef __bf16 bf16x4  __attribute__((ext_vector_type(4)));

DEV float tanh_fast(float x) {
  float e = __expf(2.0f * x);
  return 1.0f - 2.0f * __frcp_rn(e + 1.0f);
}

DEV void gl_lds16(const void* g, void* l) {
  __builtin_amdgcn_global_load_lds(
      (const __attribute__((address_space(1))) unsigned int*)g,
      (__attribute__((address_space(3))) unsigned int*)l, 16, 0, 0);
}

// ------------- prep: weight transpose->bf16 hi/lo, x0 split, dvec ---------------
struct WC { const float* W; __bf16* Wh; __bf16* Wl; };
struct Prep {
  WC w[7];
  const float* x0; __bf16* x0h; __bf16* x0l;
  const float* b_rel; const float* Wgrc; const float* b_gr; float* dvec;
};

__global__ __launch_bounds__(256) void prep_kernel(Prep pp) {
  const int y = blockIdx.y;
  if (y < 7) {
    const WC wc = pp.w[y];
    __shared__ float tile[32][33];
    int t = threadIdx.x;
    int tx = t & 31, ty = t >> 5;                     // 32 x 8
    int bx = blockIdx.x & 15, by = blockIdx.x >> 4;   // 16 x 16 tiles of 32x32
    int k0 = by * 32, n0 = bx * 32;
#pragma unroll
    for (int r = 0; r < 4; ++r) {
      int k = ty + r * 8;
      tile[k][tx] = wc.W[(size_t)(k0 + k) * 512 + n0 + tx];
    }
    __syncthreads();
#pragma unroll
    for (int r = 0; r < 4; ++r) {
      int n = ty + r * 8;
      float v = tile[tx][n];
      __bf16 h = (__bf16)v;
      wc.Wh[(size_t)(n0 + n) * 512 + k0 + tx] = h;
      wc.Wl[(size_t)(n0 + n) * 512 + k0 + tx] = (__bf16)(v - (float)h);
    }
  } else if (y == 7) {
    int i = blockIdx.x * 256 + threadIdx.x;
    if (i < 32768) {
      float4 v = ((const float4*)pp.x0)[i];
      float vv[4] = {v.x, v.y, v.z, v.w};
      bf16x4 h, l;
#pragma unroll
      for (int e = 0; e < 4; ++e) {
        __bf16 he = (__bf16)vv[e];
        h[e] = he;
        l[e] = (__bf16)(vv[e] - (float)he);
      }
      ((bf16x4*)pp.x0h)[i] = h;
      ((bf16x4*)pp.x0l)[i] = l;
    }
  } else {
    if (blockIdx.x < 2) {
      int n = blockIdx.x * 256 + threadIdx.x;
      float acc = pp.b_gr[n];
#pragma unroll 8
      for (int k = 0; k < 512; ++k) acc += pp.b_rel[k] * pp.Wgrc[(size_t)k * 512 + n];
      pp.dvec[n] = acc;
    }
  }
}

// ------------- small MFMA GEMM batch: out = act(X@W + bias + add) ---------------
// M=256, N=512, K=512. 64x64 tiles, split-precision compensated bf16.
struct MOp {
  const __bf16* Xh; const __bf16* Xl;   // [256,512]
  const __bf16* Wh; const __bf16* Wl;   // [512(n),512(k)] transposed
  const float* bias;                    // [512] or null
  const float* add;                     // [256,512] or null
  float* outf;                          // [256,512] or null
  __bf16* outh; __bf16* outl;           // [256,512] or null
  int act;                              // 1 = tanh
};
struct MBatch { MOp op[5]; };

DEV void mfma_small_body(const MOp& o) {
  const int m0 = ((int)blockIdx.x >> 3) * 64;
  const int n0 = ((int)blockIdx.x & 7) * 64;
  __shared__ __bf16 Ah[64 * 64], Al[64 * 64], Bh[64 * 64], Bl[64 * 64];
  const int t = threadIdx.x, lane = t & 63, wave = t >> 6;
  const int waveM = wave >> 1, waveN = wave & 1;
  const bool comp = (o.Xl != nullptr);

  f32x4 vzero = {0.f, 0.f, 0.f, 0.f};
  f32x4 acc[2][2];
#pragma unroll
  for (int a = 0; a < 2; ++a)
#pragma unroll
    for (int c = 0; c < 2; ++c) acc[a][c] = vzero;

  const int lr = lane >> 3, lc = (lane & 7) * 8;

  for (int k0 = 0; k0 < 512; k0 += 64) {
    __syncthreads();
#pragma unroll
    for (int r = 0; r < 2; ++r) {
      const int rb = r * 32 + wave * 8;
      gl_lds16(o.Xh + (size_t)(m0 + rb + lr) * 512 + k0 + lc, &Ah[rb * 64]);
      gl_lds16(o.Wh + (size_t)(n0 + rb + lr) * 512 + k0 + lc, &Bh[rb * 64]);
      if (comp) {
        gl_lds16(o.Xl + (size_t)(m0 + rb + lr) * 512 + k0 + lc, &Al[rb * 64]);
        gl_lds16(o.Wl + (size_t)(n0 + rb + lr) * 512 + k0 + lc, &Bl[rb * 64]);
      }
    }
    __syncthreads();
#pragma unroll
    for (int kk = 0; kk < 2; ++kk) {
      const int koff = kk * 32 + (lane >> 4) * 8;
      const int ml = lane & 15;
      bf16x8 ah[2], bh[2], al[2], bl[2];
#pragma unroll
      for (int tm = 0; tm < 2; ++tm)
        ah[tm] = *(const bf16x8*)&Ah[(waveM * 32 + tm * 16 + ml) * 64 + koff];
#pragma unroll
      for (int tn = 0; tn < 2; ++tn)
        bh[tn] = *(const bf16x8*)&Bh[(waveN * 32 + tn * 16 + ml) * 64 + koff];
      if (comp) {
#pragma unroll
        for (int tm = 0; tm < 2; ++tm)
          al[tm] = *(const bf16x8*)&Al[(waveM * 32 + tm * 16 + ml) * 64 + koff];
#pragma unroll
        for (int tn = 0; tn < 2; ++tn)
          bl[tn] = *(const bf16x8*)&Bl[(waveN * 32 + tn * 16 + ml) * 64 + koff];
      }
#pragma unroll
      for (int tm = 0; tm < 2; ++tm)
#pragma unroll
        for (int tn = 0; tn < 2; ++tn) {
          acc[tm][tn] = __builtin_amdgcn_mfma_f32_16x16x32_bf16(ah[tm], bh[tn], acc[tm][tn], 0, 0, 0);
          if (comp) {
            acc[tm][tn] = __builtin_amdgcn_mfma_f32_16x16x32_bf16(ah[tm], bl[tn], acc[tm][tn], 0, 0, 0);
            acc[tm][tn] = __builtin_amdgcn_mfma_f32_16x16x32_bf16(al[tm], bh[tn], acc[tm][tn], 0, 0, 0);
          }
        }
    }
  }

  const int quad = lane >> 4, cl = lane & 15;
#pragma unroll
  for (int tm = 0; tm < 2; ++tm) {
#pragma unroll
    for (int r = 0; r < 4; ++r) {
      const int row = m0 + waveM * 32 + tm * 16 + quad * 4 + r;
#pragma unroll
      for (int tn = 0; tn < 2; ++tn) {
        const int col = n0 + waveN * 32 + tn * 16 + cl;
        float v = acc[tm][tn][r];
        if (o.bias) v += o.bias[col];
        if (o.add) v += o.add[(size_t)row * 512 + col];
        if (o.act) v = tanh_fast(v);
        if (o.outf) o.outf[(size_t)row * 512 + col] = v;
        if (o.outh) {
          __bf16 h = (__bf16)v;
          o.outh[(size_t)row * 512 + col] = h;
          o.outl[(size_t)row * 512 + col] = (__bf16)(v - (float)h);
        }
      }
    }
  }
}

__global__ __launch_bounds__(256, 2) void mfma_small_kernel(MBatch batch) {
  mfma_small_body(batch.op[blockIdx.y]);
}

// rel1 element slice: R1[e..e+7] = tanh(A[bi]+C[b,j]) for vec8 unit u
DEV void rel1_unit(const float* __restrict__ A, const float* __restrict__ C,
                   __bf16* __restrict__ R1, size_t u) {
  size_t e = u * 8;
  int d = (int)(e & 511);
  int j = (int)((e >> 9) & 127);
  int bi = (int)(e >> 16);         // b*128 + i
  int b = bi >> 7;
  const float* ap = &A[(size_t)bi * 512 + d];
  const float* cp = &C[((size_t)(b * 128 + j)) * 512 + d];
  float av[8], cv[8];
  *(float4*)&av[0] = *(const float4*)ap;
  *(float4*)&av[4] = *(const float4*)(ap + 4);
  *(float4*)&cv[0] = *(const float4*)cp;
  *(float4*)&cv[4] = *(const float4*)(cp + 4);
  bf16x8 o;
#pragma unroll
  for (int k = 0; k < 8; ++k) o[k] = (__bf16)tanh_fast(av[k] + cv[k]);
  *(bf16x8*)&R1[e] = o;
}

// m3 batch (3 GEMM ops, y=0..2, x<32) + rel1 slice (y=3, x=0..255 grid-stride).
__global__ __launch_bounds__(256, 2) void m3_rel1_kernel(
    MBatch batch, const float* __restrict__ A, const float* __restrict__ C,
    __bf16* __restrict__ R1) {
  if (blockIdx.y == 3) {
    // 2,097,152 vec8 units over 256 blocks x 256 thr -> 32 units/thread
    size_t base = (size_t)blockIdx.x * 256 + threadIdx.x;
#pragma unroll 1
    for (int it = 0; it < 32; ++it)
      rel1_unit(A, C, R1, base + (size_t)it * 65536);
    return;
  }
  if (blockIdx.x >= 32) return;
  mfma_small_body(batch.op[blockIdx.y]);
}

// ------------- big MFMA GEMM: [32768,512] @ Wt^T, K=512, 32x32x16 --------------
// MODE 1: out bf16 tanh(acc + P[i] + Q[j]);  MODE 2: out f32 (acc + bias)
// LDS: row-stride 64 bf16 with +8 bf16 pad every 8 rows.
// XCD swizzle: grid 1024 (%8==0) -> blk=(d%8)*128+d/8.
constexpr int BM = 128, BN = 128, BK = 64;
DEV int lds_off(int row) { return row * 64 + (row >> 3) * 8; }

template <int MODE>
__global__ __launch_bounds__(256, 2) void big_gemm_kernel(
    const __bf16* __restrict__ Ab, const __bf16* __restrict__ Wt,
    const float* __restrict__ P, const float* __restrict__ Q,
    const float* __restrict__ bias, __bf16* __restrict__ outb,
    float* __restrict__ outf) {
  __shared__ __bf16 As[BM * BK + 16 * 8];
  __shared__ __bf16 Bs[BN * BK + 16 * 8];
  const int t = threadIdx.x;
  const int lane = t & 63;
  const int wave = t >> 6;
  const int blk = ((int)blockIdx.x & 7) * 128 + ((int)blockIdx.x >> 3);
  const int bm = blk >> 2;                      // (b*128 + i)
  const int n0 = (blk & 3) * BN;
  const size_t r0 = (size_t)bm * BM;
  const int b = bm >> 7;
  const int i = bm & 127;
  const int waveM = wave >> 1, waveN = wave & 1;

  f32x16 acc[2][2];
#pragma unroll
  for (int a = 0; a < 2; ++a)
#pragma unroll
    for (int c = 0; c < 2; ++c) acc[a][c] = (f32x16)0.f;

  for (int k0 = 0; k0 < 512; k0 += BK) {
    __syncthreads();
#pragma unroll
    for (int p2 = 0; p2 < 4; ++p2) {
      int rowg = wave * 32 + p2 * 8;
      const __bf16* ga = Ab + (r0 + rowg + (lane >> 3)) * 512 + k0 + (lane & 7) * 8;
      gl_lds16(ga, &As[lds_off(rowg)]);
      const __bf16* gb = Wt + (size_t)(n0 + rowg + (lane >> 3)) * 512 + k0 + (lane & 7) * 8;
      gl_lds16(gb, &Bs[lds_off(rowg)]);
    }
    __syncthreads();
    const int ml = lane & 31;
    const int kl = (lane >> 5) * 8;
#pragma unroll
    for (int ks = 0; ks < 4; ++ks) {
      const int koff = ks * 16 + kl;
      bf16x8 af[2], bfr[2];
#pragma unroll
      for (int tm = 0; tm < 2; ++tm)
        af[tm] = *(const bf16x8*)&As[lds_off(waveM * 64 + tm * 32 + ml) + koff];
#pragma unroll
      for (int tn = 0; tn < 2; ++tn)
        bfr[tn] = *(const bf16x8*)&Bs[lds_off(waveN * 64 + tn * 32 + ml) + koff];
#pragma unroll
      for (int tm = 0; tm < 2; ++tm)
#pragma unroll
        for (int tn = 0; tn < 2; ++tn)
          acc[tm][tn] = __builtin_amdgcn_mfma_f32_32x32x16_bf16(af[tm], bfr[tn], acc[tm][tn], 0, 0, 0);
    }
  }

  const int cl = lane & 31, lg = lane >> 5;
#pragma unroll
  for (int tm = 0; tm < 2; ++tm) {
#pragma unroll
    for (int tn = 0; tn < 2; ++tn) {
      const int col = n0 + waveN * 64 + tn * 32 + cl;
      float pv;
      if (MODE == 2) pv = bias[col];
      else pv = P[((size_t)(b * 128 + i)) * 512 + col];
#pragma unroll
      for (int reg = 0; reg < 16; ++reg) {
        const int row = waveM * 64 + tm * 32 + (reg & 3) + 8 * (reg >> 2) + 4 * lg;  // j
        float v = acc[tm][tn][reg] + pv;
        if (MODE == 2) {
          outf[(r0 + row) * 512 + col] = v;
        } else {
          v += Q[((size_t)(b * 128 + row)) * 512 + col];
          outb[(r0 + row) * 512 + col] = (__bf16)tanh_fast(v);
        }
      }
    }
  }
}

// ------------- softmax over axis i (no max pass: |s| bounded), then sum over j --
__global__ __launch_bounds__(256) void softmax_l_kernel(
    const float* __restrict__ S, float* __restrict__ Lb) {
  int idx = blockIdx.x * 256 + threadIdx.x;   // = (b*128 + j)*512 + d
  int d = idx & 511;
  int j = (idx >> 9) & 127;
  int b = idx >> 16;
  const float* p = S + ((size_t)b * 16384 + j) * 512 + d;  // i = 0
  float l = 0.f;
#pragma unroll 8
  for (int ii = 0; ii < 128; ++ii) l += __expf(p[(size_t)ii * 65536]);
  Lb[idx] = __frcp_rn(l);
}

__global__ __launch_bounds__(256) void softmax_out_kernel(
    const float* __restrict__ S, const float* __restrict__ Lb,
    float* __restrict__ outp) {
  int idx = blockIdx.x * 256 + threadIdx.x;   // = (b*128 + i)*512 + d
  int d = idx & 511;
  int i = (idx >> 9) & 127;
  int b = idx >> 16;
  const float* sp = S + ((size_t)(b * 128 + i)) * 65536 + d;  // j = 0
  const float* lp = Lb + (size_t)b * 65536 + d;
  float acc = 0.f;
#pragma unroll 8
  for (int jj = 0; jj < 128; ++jj) {
    float s = sp[(size_t)jj * 512];
    acc += __expf(s) * lp[(size_t)jj * 512] * s;
  }
  outp[idx] = acc;
}

// --------------------------------------------------------------------------------
extern "C" void kernel_launch(void* const* d_in, const int* in_sizes, int n_in,
                              void* d_out, int out_size, void* d_ws, size_t ws_size,
                              hipStream_t stream) {
  const float* x0    = (const float*)d_in[0];
  const float* W_rel = (const float*)d_in[1];
  const float* b_rel = (const float*)d_in[2];
  const float* W_go  = (const float*)d_in[3];
  const float* b_go  = (const float*)d_in[4];
  const float* W_gr  = (const float*)d_in[5];
  const float* b_gr  = (const float*)d_in[6];
  const float* W_esa = (const float*)d_in[7];
  const float* b_esa = (const float*)d_in[8];

  const float* Wrel_top = W_rel;
  const float* Wrel_bot = W_rel + 512 * 512;
  const float* Wgr_a = W_gr;
  const float* Wgr_b = W_gr + 512 * 512;
  const float* Wgr_c = W_gr + 2 * 512 * 512;

  char* ws = (char*)d_ws;
  size_t off = 0;
  auto alloc = [&](size_t bytes) -> void* {
    void* p = ws + off;
    off += (bytes + 255) & ~(size_t)255;
    return p;
  };
  const size_t NREL = 16777216ull;  // B*N*N*D
  float*  S  = (float*)alloc(NREL * 4);        // 64 MB
  __bf16* R1 = (__bf16*)alloc(NREL * 2);       // 32 MB
  __bf16* R2 = (__bf16*)alloc(NREL * 2);       // 32 MB
  float* p0t  = (float*)alloc(131072 * 4);
  float* q0t  = (float*)alloc(131072 * 4);
  float* Abuf = (float*)alloc(131072 * 4);
  float* Cbuf = (float*)alloc(131072 * 4);
  float* p1   = (float*)alloc(131072 * 4);
  float* q1   = (float*)alloc(131072 * 4);
  float* p2   = (float*)alloc(131072 * 4);
  float* q2   = (float*)alloc(131072 * 4);
  float* dvec = (float*)alloc(512 * 4);
  float* Lb   = (float*)alloc(131072 * 4);
  __bf16* x0h = (__bf16*)alloc(131072 * 2);
  __bf16* x0l = (__bf16*)alloc(131072 * 2);
  __bf16* x1h = (__bf16*)alloc(131072 * 2);
  __bf16* x1l = (__bf16*)alloc(131072 * 2);
  __bf16* x2h = (__bf16*)alloc(131072 * 2);
  __bf16* x2l = (__bf16*)alloc(131072 * 2);
  __bf16* u0h = (__bf16*)alloc(131072 * 2);
  __bf16* u0l = (__bf16*)alloc(131072 * 2);
  __bf16* v0h = (__bf16*)alloc(131072 * 2);
  __bf16* v0l = (__bf16*)alloc(131072 * 2);
  __bf16* Wgo_h = (__bf16*)alloc(262144 * 2);
  __bf16* Wgo_l = (__bf16*)alloc(262144 * 2);
  __bf16* Wrt_h = (__bf16*)alloc(262144 * 2);
  __bf16* Wrt_l = (__bf16*)alloc(262144 * 2);
  __bf16* Wrb_h = (__bf16*)alloc(262144 * 2);
  __bf16* Wrb_l = (__bf16*)alloc(262144 * 2);
  __bf16* Wga_h = (__bf16*)alloc(262144 * 2);
  __bf16* Wga_l = (__bf16*)alloc(262144 * 2);
  __bf16* Wgb_h = (__bf16*)alloc(262144 * 2);
  __bf16* Wgb_l = (__bf16*)alloc(262144 * 2);
  __bf16* Wgc_h = (__bf16*)alloc(262144 * 2);
  __bf16* Wgc_l = (__bf16*)alloc(262144 * 2);
  __bf16* Wes_h = (__bf16*)alloc(262144 * 2);
  __bf16* Wes_l = (__bf16*)alloc(262144 * 2);

  float* x3out  = (float*)d_out;             // output 0
  float* relout = (float*)d_out + 131072;    // output 1

  Prep pp;
  pp.w[0] = {W_go, Wgo_h, Wgo_l};
  pp.w[1] = {Wrel_top, Wrt_h, Wrt_l};
  pp.w[2] = {Wrel_bot, Wrb_h, Wrb_l};
  pp.w[3] = {Wgr_a, Wga_h, Wga_l};
  pp.w[4] = {Wgr_b, Wgb_h, Wgb_l};
  pp.w[5] = {Wgr_c, Wgc_h, Wgc_l};
  pp.w[6] = {W_esa, Wes_h, Wes_l};
  pp.x0 = x0; pp.x0h = x0h; pp.x0l = x0l;
  pp.b_rel = b_rel; pp.Wgrc = Wgr_c; pp.b_gr = b_gr; pp.dvec = dvec;
  prep_kernel<<<dim3(256, 9), 256, 0, stream>>>(pp);

  MBatch m1 = {};
  m1.op[0] = {x0h, x0l, Wgo_h, Wgo_l, b_go, nullptr, nullptr, x1h, x1l, 1};
  m1.op[1] = {x0h, x0l, Wrt_h, Wrt_l, nullptr, nullptr, nullptr, u0h, u0l, 0};
  m1.op[2] = {x0h, x0l, Wrb_h, Wrb_l, nullptr, nullptr, nullptr, v0h, v0l, 0};
  m1.op[3] = {x0h, x0l, Wga_h, Wga_l, nullptr, nullptr, p0t, nullptr, nullptr, 0};
  m1.op[4] = {x0h, x0l, Wgb_h, Wgb_l, nullptr, nullptr, q0t, nullptr, nullptr, 0};
  mfma_small_kernel<<<dim3(32, 5), 256, 0, stream>>>(m1);

  MBatch m2 = {};
  m2.op[0] = {x1h, x1l, Wgo_h, Wgo_l, b_go, nullptr, nullptr, x2h, x2l, 1};
  m2.op[1] = {u0h, u0l, Wgc_h, Wgc_l, dvec, p0t, Abuf, nullptr, nullptr, 0};
  m2.op[2] = {v0h, v0l, Wgc_h, Wgc_l, nullptr, q0t, Cbuf, nullptr, nullptr, 0};
  m2.op[3] = {x1h, x1l, Wga_h, Wga_l, b_gr, nullptr, p1, nullptr, nullptr, 0};
  m2.op[4] = {x1h, x1l, Wgb_h, Wgb_l, nullptr, nullptr, q1, nullptr, nullptr, 0};
  mfma_small_kernel<<<dim3(32, 5), 256, 0, stream>>>(m2);

  // m3 batch + rel1 fold: y=0..2 GEMM ops (x<32), y=3 rel1 (256 blocks)
  MBatch m3 = {};
  m3.op[0] = {x2h, x2l, Wgo_h, Wgo_l, b_go, nullptr, x3out, nullptr, nullptr, 1};
  m3.op[1] = {x2h, x2l, Wga_h, Wga_l, b_gr, nullptr, p2, nullptr, nullptr, 0};
  m3.op[2] = {x2h, x2l, Wgb_h, Wgb_l, nullptr, nullptr, q2, nullptr, nullptr, 0};
  m3_rel1_kernel<<<dim3(256, 4), 256, 0, stream>>>(m3, Abuf, Cbuf, R1);

  // rel2 = tanh(rel1@Wgr_c + p1[i] + q1[j])
  big_gemm_kernel<1><<<1024, 256, 0, stream>>>(R1, Wgc_h, p1, q1, nullptr, R2, nullptr);
  // rel3 = tanh(rel2@Wgr_c + p2[i] + q2[j])
  big_gemm_kernel<1><<<1024, 256, 0, stream>>>(R2, Wgc_h, p2, q2, nullptr, R1, nullptr);
  // S = rel3@W_esa + b_esa
  big_gemm_kernel<2><<<1024, 256, 0, stream>>>(R1, Wes_h, nullptr, nullptr, b_esa, nullptr, S);

  softmax_l_kernel<<<512, 256, 0, stream>>>(S, Lb);
  softmax_out_kernel<<<512, 256, 0, stream>>>(S, Lb, relout);
}

// Round 9
// 252.491 us; speedup vs baseline: 1.0468x; 1.0426x over previous
//
#include <hip/hip_runtime.h>
#include <hip/hip_bf16.h>
#include <stdint.h>

// B=2, N=128, D=512, LAYERS=3.
// Algebraic reduction: the [B,N,N,*] concat-GEMMs decompose into rank terms.
// Only rel@Wgr_c (x2) + rel3@W_esa are big MFMA GEMMs; rel1 = tanh(A[i]+C[j]).
// Softmax over axis i without the max pass (|s|<=~23 << f32 exp overflow).
// Round-9 delta vs round-8 (263.2us): T2 XOR bank-swizzle on BOTH GEMM LDS
// tiles.  Audit showed the old layouts put a wave's 64 ds_read_b128 lanes on
// 4-5 of 8 16B slot-groups (pad moved 8-row groups together; smalls had no
// row term at all) -> ~2x LDS conflict, LDS = critical path (explains the
// round-6 counted-vmcnt null, per the T2/T3 regime gate).  New layout:
// byte(row,col) = row*128 + (colB ^ ((row&7)<<4)); gl_lds16 stays linear-dest
// with the involution pre-applied to the GLOBAL source (per-lane constant
// granule = (lane&7)^(lane>>3), since every 1KB chunk starts at row%8==0).
// Same data, same MFMA order -> bit-identical results.
// Kept: XCD swizzle on big GEMMs (r5, -7.6us), rel1 folded into m3 (r8).

#define DEV static __device__ __forceinline__

typedef float  f32x4   __attribute__((ext_vector_type(4)));
typedef float  f32x16  __attribute__((ext_vector_type(16)));
typedef __bf16 bf16x8  __attribute__((ext_vector_type(8)));
typedef __bf16 bf16x4  __attribute__((ext_vector_type(4)));

DEV float tanh_fast(float x) {
  float e = __expf(2.0f * x);
  return 1.0f - 2.0f * __frcp_rn(e + 1.0f);
}

DEV void gl_lds16(const void* g, void* l) {
  __builtin_amdgcn_global_load_lds(
      (const __attribute__((address_space(1))) unsigned int*)g,
      (__attribute__((address_space(3))) unsigned int*)l, 16, 0, 0);
}

// swizzled LDS byte address for a [*, 64 bf16] row-major tile (128B rows)
DEV int swz(int row, int kbyte) { return row * 128 + (kbyte ^ ((row & 7) << 4)); }

// ------------- prep: weight transpose->bf16 hi/lo, x0 split, dvec ---------------
struct WC { const float* W; __bf16* Wh; __bf16* Wl; };
struct Prep {
  WC w[7];
  const float* x0; __bf16* x0h; __bf16* x0l;
  const float* b_rel; const float* Wgrc; const float* b_gr; float* dvec;
};

__global__ __launch_bounds__(256) void prep_kernel(Prep pp) {
  const int y = blockIdx.y;
  if (y < 7) {
    const WC wc = pp.w[y];
    __shared__ float tile[32][33];
    int t = threadIdx.x;
    int tx = t & 31, ty = t >> 5;                     // 32 x 8
    int bx = blockIdx.x & 15, by = blockIdx.x >> 4;   // 16 x 16 tiles of 32x32
    int k0 = by * 32, n0 = bx * 32;
#pragma unroll
    for (int r = 0; r < 4; ++r) {
      int k = ty + r * 8;
      tile[k][tx] = wc.W[(size_t)(k0 + k) * 512 + n0 + tx];
    }
    __syncthreads();
#pragma unroll
    for (int r = 0; r < 4; ++r) {
      int n = ty + r * 8;
      float v = tile[tx][n];
      __bf16 h = (__bf16)v;
      wc.Wh[(size_t)(n0 + n) * 512 + k0 + tx] = h;
      wc.Wl[(size_t)(n0 + n) * 512 + k0 + tx] = (__bf16)(v - (float)h);
    }
  } else if (y == 7) {
    int i = blockIdx.x * 256 + threadIdx.x;
    if (i < 32768) {
      float4 v = ((const float4*)pp.x0)[i];
      float vv[4] = {v.x, v.y, v.z, v.w};
      bf16x4 h, l;
#pragma unroll
      for (int e = 0; e < 4; ++e) {
        __bf16 he = (__bf16)vv[e];
        h[e] = he;
        l[e] = (__bf16)(vv[e] - (float)he);
      }
      ((bf16x4*)pp.x0h)[i] = h;
      ((bf16x4*)pp.x0l)[i] = l;
    }
  } else {
    if (blockIdx.x < 2) {
      int n = blockIdx.x * 256 + threadIdx.x;
      float acc = pp.b_gr[n];
#pragma unroll 8
      for (int k = 0; k < 512; ++k) acc += pp.b_rel[k] * pp.Wgrc[(size_t)k * 512 + n];
      pp.dvec[n] = acc;
    }
  }
}

// ------------- small MFMA GEMM batch: out = act(X@W + bias + add) ---------------
// M=256, N=512, K=512. 64x64 tiles, split-precision compensated bf16.
struct MOp {
  const __bf16* Xh; const __bf16* Xl;   // [256,512]
  const __bf16* Wh; const __bf16* Wl;   // [512(n),512(k)] transposed
  const float* bias;                    // [512] or null
  const float* add;                     // [256,512] or null
  float* outf;                          // [256,512] or null
  __bf16* outh; __bf16* outl;           // [256,512] or null
  int act;                              // 1 = tanh
};
struct MBatch { MOp op[5]; };

DEV void mfma_small_body(const MOp& o) {
  const int m0 = ((int)blockIdx.x >> 3) * 64;
  const int n0 = ((int)blockIdx.x & 7) * 64;
  __shared__ __bf16 Ah[64 * 64], Al[64 * 64], Bh[64 * 64], Bl[64 * 64];
  const int t = threadIdx.x, lane = t & 63, wave = t >> 6;
  const int waveM = wave >> 1, waveN = wave & 1;
  const bool comp = (o.Xl != nullptr);

  f32x4 vzero = {0.f, 0.f, 0.f, 0.f};
  f32x4 acc[2][2];
#pragma unroll
  for (int a = 0; a < 2; ++a)
#pragma unroll
    for (int c = 0; c < 2; ++c) acc[a][c] = vzero;

  const int lr = lane >> 3;
  const int lc = ((lane & 7) ^ lr) * 8;   // pre-swizzled source granule

  for (int k0 = 0; k0 < 512; k0 += 64) {
    __syncthreads();
#pragma unroll
    for (int r = 0; r < 2; ++r) {
      const int rb = r * 32 + wave * 8;
      gl_lds16(o.Xh + (size_t)(m0 + rb + lr) * 512 + k0 + lc, &Ah[rb * 64]);
      gl_lds16(o.Wh + (size_t)(n0 + rb + lr) * 512 + k0 + lc, &Bh[rb * 64]);
      if (comp) {
        gl_lds16(o.Xl + (size_t)(m0 + rb + lr) * 512 + k0 + lc, &Al[rb * 64]);
        gl_lds16(o.Wl + (size_t)(n0 + rb + lr) * 512 + k0 + lc, &Bl[rb * 64]);
      }
    }
    __syncthreads();
#pragma unroll
    for (int kk = 0; kk < 2; ++kk) {
      const int kb = kk * 64 + (lane >> 4) * 16;   // byte offset within row
      const int ml = lane & 15;
      bf16x8 ah[2], bh[2], al[2], bl[2];
#pragma unroll
      for (int tm = 0; tm < 2; ++tm)
        ah[tm] = *(const bf16x8*)((const char*)Ah + swz(waveM * 32 + tm * 16 + ml, kb));
#pragma unroll
      for (int tn = 0; tn < 2; ++tn)
        bh[tn] = *(const bf16x8*)((const char*)Bh + swz(waveN * 32 + tn * 16 + ml, kb));
      if (comp) {
#pragma unroll
        for (int tm = 0; tm < 2; ++tm)
          al[tm] = *(const bf16x8*)((const char*)Al + swz(waveM * 32 + tm * 16 + ml, kb));
#pragma unroll
        for (int tn = 0; tn < 2; ++tn)
          bl[tn] = *(const bf16x8*)((const char*)Bl + swz(waveN * 32 + tn * 16 + ml, kb));
      }
#pragma unroll
      for (int tm = 0; tm < 2; ++tm)
#pragma unroll
        for (int tn = 0; tn < 2; ++tn) {
          acc[tm][tn] = __builtin_amdgcn_mfma_f32_16x16x32_bf16(ah[tm], bh[tn], acc[tm][tn], 0, 0, 0);
          if (comp) {
            acc[tm][tn] = __builtin_amdgcn_mfma_f32_16x16x32_bf16(ah[tm], bl[tn], acc[tm][tn], 0, 0, 0);
            acc[tm][tn] = __builtin_amdgcn_mfma_f32_16x16x32_bf16(al[tm], bh[tn], acc[tm][tn], 0, 0, 0);
          }
        }
    }
  }

  const int quad = lane >> 4, cl = lane & 15;
#pragma unroll
  for (int tm = 0; tm < 2; ++tm) {
#pragma unroll
    for (int r = 0; r < 4; ++r) {
      const int row = m0 + waveM * 32 + tm * 16 + quad * 4 + r;
#pragma unroll
      for (int tn = 0; tn < 2; ++tn) {
        const int col = n0 + waveN * 32 + tn * 16 + cl;
        float v = acc[tm][tn][r];
        if (o.bias) v += o.bias[col];
        if (o.add) v += o.add[(size_t)row * 512 + col];
        if (o.act) v = tanh_fast(v);
        if (o.outf) o.outf[(size_t)row * 512 + col] = v;
        if (o.outh) {
          __bf16 h = (__bf16)v;
          o.outh[(size_t)row * 512 + col] = h;
          o.outl[(size_t)row * 512 + col] = (__bf16)(v - (float)h);
        }
      }
    }
  }
}

__global__ __launch_bounds__(256, 2) void mfma_small_kernel(MBatch batch) {
  mfma_small_body(batch.op[blockIdx.y]);
}

// rel1 element slice: R1[e..e+7] = tanh(A[bi]+C[b,j]) for vec8 unit u
DEV void rel1_unit(const float* __restrict__ A, const float* __restrict__ C,
                   __bf16* __restrict__ R1, size_t u) {
  size_t e = u * 8;
  int d = (int)(e & 511);
  int j = (int)((e >> 9) & 127);
  int bi = (int)(e >> 16);         // b*128 + i
  int b = bi >> 7;
  const float* ap = &A[(size_t)bi * 512 + d];
  const float* cp = &C[((size_t)(b * 128 + j)) * 512 + d];
  float av[8], cv[8];
  *(float4*)&av[0] = *(const float4*)ap;
  *(float4*)&av[4] = *(const float4*)(ap + 4);
  *(float4*)&cv[0] = *(const float4*)cp;
  *(float4*)&cv[4] = *(const float4*)(cp + 4);
  bf16x8 o;
#pragma unroll
  for (int k = 0; k < 8; ++k) o[k] = (__bf16)tanh_fast(av[k] + cv[k]);
  *(bf16x8*)&R1[e] = o;
}

// m3 batch (3 GEMM ops, y=0..2, x<32) + rel1 slice (y=3, x=0..255 grid-stride).
__global__ __launch_bounds__(256, 2) void m3_rel1_kernel(
    MBatch batch, const float* __restrict__ A, const float* __restrict__ C,
    __bf16* __restrict__ R1) {
  if (blockIdx.y == 3) {
    size_t base = (size_t)blockIdx.x * 256 + threadIdx.x;
#pragma unroll 1
    for (int it = 0; it < 32; ++it)
      rel1_unit(A, C, R1, base + (size_t)it * 65536);
    return;
  }
  if (blockIdx.x >= 32) return;
  mfma_small_body(batch.op[blockIdx.y]);
}

// ------------- big MFMA GEMM: [32768,512] @ Wt^T, K=512, 32x32x16 --------------
// MODE 1: out bf16 tanh(acc + P[i] + Q[j]);  MODE 2: out f32 (acc + bias)
// LDS: linear 128B rows, T2 XOR swizzle (read side + pre-swizzled source).
// XCD swizzle: grid 1024 (%8==0) -> blk=(d%8)*128+d/8.
constexpr int BM = 128, BN = 128, BK = 64;

template <int MODE>
__global__ __launch_bounds__(256, 2) void big_gemm_kernel(
    const __bf16* __restrict__ Ab, const __bf16* __restrict__ Wt,
    const float* __restrict__ P, const float* __restrict__ Q,
    const float* __restrict__ bias, __bf16* __restrict__ outb,
    float* __restrict__ outf) {
  __shared__ __bf16 As[BM * BK];
  __shared__ __bf16 Bs[BN * BK];
  const int t = threadIdx.x;
  const int lane = t & 63;
  const int wave = t >> 6;
  const int blk = ((int)blockIdx.x & 7) * 128 + ((int)blockIdx.x >> 3);
  const int bm = blk >> 2;                      // (b*128 + i)
  const int n0 = (blk & 3) * BN;
  const size_t r0 = (size_t)bm * BM;
  const int b = bm >> 7;
  const int i = bm & 127;
  const int waveM = wave >> 1, waveN = wave & 1;

  const int lr = lane >> 3;
  const int lc = ((lane & 7) ^ lr) * 8;   // pre-swizzled source granule

  f32x16 acc[2][2];
#pragma unroll
  for (int a = 0; a < 2; ++a)
#pragma unroll
    for (int c = 0; c < 2; ++c) acc[a][c] = (f32x16)0.f;

  for (int k0 = 0; k0 < 512; k0 += BK) {
    __syncthreads();
#pragma unroll
    for (int p2 = 0; p2 < 4; ++p2) {
      int rowg = wave * 32 + p2 * 8;
      const __bf16* ga = Ab + (r0 + rowg + lr) * 512 + k0 + lc;
      gl_lds16(ga, &As[rowg * 64]);
      const __bf16* gb = Wt + (size_t)(n0 + rowg + lr) * 512 + k0 + lc;
      gl_lds16(gb, &Bs[rowg * 64]);
    }
    __syncthreads();
    const int ml = lane & 31;
    const int klb = (lane >> 5) * 16;           // byte
#pragma unroll
    for (int ks = 0; ks < 4; ++ks) {
      const int kb = ks * 32 + klb;             // byte offset within row
      bf16x8 af[2], bfr[2];
#pragma unroll
      for (int tm = 0; tm < 2; ++tm)
        af[tm] = *(const bf16x8*)((const char*)As + swz(waveM * 64 + tm * 32 + ml, kb));
#pragma unroll
      for (int tn = 0; tn < 2; ++tn)
        bfr[tn] = *(const bf16x8*)((const char*)Bs + swz(waveN * 64 + tn * 32 + ml, kb));
#pragma unroll
      for (int tm = 0; tm < 2; ++tm)
#pragma unroll
        for (int tn = 0; tn < 2; ++tn)
          acc[tm][tn] = __builtin_amdgcn_mfma_f32_32x32x16_bf16(af[tm], bfr[tn], acc[tm][tn], 0, 0, 0);
    }
  }

  const int cl = lane & 31, lg = lane >> 5;
#pragma unroll
  for (int tm = 0; tm < 2; ++tm) {
#pragma unroll
    for (int tn = 0; tn < 2; ++tn) {
      const int col = n0 + waveN * 64 + tn * 32 + cl;
      float pv;
      if (MODE == 2) pv = bias[col];
      else pv = P[((size_t)(b * 128 + i)) * 512 + col];
#pragma unroll
      for (int reg = 0; reg < 16; ++reg) {
        const int row = waveM * 64 + tm * 32 + (reg & 3) + 8 * (reg >> 2) + 4 * lg;  // j
        float v = acc[tm][tn][reg] + pv;
        if (MODE == 2) {
          outf[(r0 + row) * 512 + col] = v;
        } else {
          v += Q[((size_t)(b * 128 + row)) * 512 + col];
          outb[(r0 + row) * 512 + col] = (__bf16)tanh_fast(v);
        }
      }
    }
  }
}

// ------------- softmax over axis i (no max pass: |s| bounded), then sum over j --
__global__ __launch_bounds__(256) void softmax_l_kernel(
    const float* __restrict__ S, float* __restrict__ Lb) {
  int idx = blockIdx.x * 256 + threadIdx.x;   // = (b*128 + j)*512 + d
  int d = idx & 511;
  int j = (idx >> 9) & 127;
  int b = idx >> 16;
  const float* p = S + ((size_t)b * 16384 + j) * 512 + d;  // i = 0
  float l = 0.f;
#pragma unroll 8
  for (int ii = 0; ii < 128; ++ii) l += __expf(p[(size_t)ii * 65536]);
  Lb[idx] = __frcp_rn(l);
}

__global__ __launch_bounds__(256) void softmax_out_kernel(
    const float* __restrict__ S, const float* __restrict__ Lb,
    float* __restrict__ outp) {
  int idx = blockIdx.x * 256 + threadIdx.x;   // = (b*128 + i)*512 + d
  int d = idx & 511;
  int i = (idx >> 9) & 127;
  int b = idx >> 16;
  const float* sp = S + ((size_t)(b * 128 + i)) * 65536 + d;  // j = 0
  const float* lp = Lb + (size_t)b * 65536 + d;
  float acc = 0.f;
#pragma unroll 8
  for (int jj = 0; jj < 128; ++jj) {
    float s = sp[(size_t)jj * 512];
    acc += __expf(s) * lp[(size_t)jj * 512] * s;
  }
  outp[idx] = acc;
}

// --------------------------------------------------------------------------------
extern "C" void kernel_launch(void* const* d_in, const int* in_sizes, int n_in,
                              void* d_out, int out_size, void* d_ws, size_t ws_size,
                              hipStream_t stream) {
  const float* x0    = (const float*)d_in[0];
  const float* W_rel = (const float*)d_in[1];
  const float* b_rel = (const float*)d_in[2];
  const float* W_go  = (const float*)d_in[3];
  const float* b_go  = (const float*)d_in[4];
  const float* W_gr  = (const float*)d_in[5];
  const float* b_gr  = (const float*)d_in[6];
  const float* W_esa = (const float*)d_in[7];
  const float* b_esa = (const float*)d_in[8];

  const float* Wrel_top = W_rel;
  const float* Wrel_bot = W_rel + 512 * 512;
  const float* Wgr_a = W_gr;
  const float* Wgr_b = W_gr + 512 * 512;
  const float* Wgr_c = W_gr + 2 * 512 * 512;

  char* ws = (char*)d_ws;
  size_t off = 0;
  auto alloc = [&](size_t bytes) -> void* {
    void* p = ws + off;
    off += (bytes + 255) & ~(size_t)255;
    return p;
  };
  const size_t NREL = 16777216ull;  // B*N*N*D
  float*  S  = (float*)alloc(NREL * 4);        // 64 MB
  __bf16* R1 = (__bf16*)alloc(NREL * 2);       // 32 MB
  __bf16* R2 = (__bf16*)alloc(NREL * 2);       // 32 MB
  float* p0t  = (float*)alloc(131072 * 4);
  float* q0t  = (float*)alloc(131072 * 4);
  float* Abuf = (float*)alloc(131072 * 4);
  float* Cbuf = (float*)alloc(131072 * 4);
  float* p1   = (float*)alloc(131072 * 4);
  float* q1   = (float*)alloc(131072 * 4);
  float* p2   = (float*)alloc(131072 * 4);
  float* q2   = (float*)alloc(131072 * 4);
  float* dvec = (float*)alloc(512 * 4);
  float* Lb   = (float*)alloc(131072 * 4);
  __bf16* x0h = (__bf16*)alloc(131072 * 2);
  __bf16* x0l = (__bf16*)alloc(131072 * 2);
  __bf16* x1h = (__bf16*)alloc(131072 * 2);
  __bf16* x1l = (__bf16*)alloc(131072 * 2);
  __bf16* x2h = (__bf16*)alloc(131072 * 2);
  __bf16* x2l = (__bf16*)alloc(131072 * 2);
  __bf16* u0h = (__bf16*)alloc(131072 * 2);
  __bf16* u0l = (__bf16*)alloc(131072 * 2);
  __bf16* v0h = (__bf16*)alloc(131072 * 2);
  __bf16* v0l = (__bf16*)alloc(131072 * 2);
  __bf16* Wgo_h = (__bf16*)alloc(262144 * 2);
  __bf16* Wgo_l = (__bf16*)alloc(262144 * 2);
  __bf16* Wrt_h = (__bf16*)alloc(262144 * 2);
  __bf16* Wrt_l = (__bf16*)alloc(262144 * 2);
  __bf16* Wrb_h = (__bf16*)alloc(262144 * 2);
  __bf16* Wrb_l = (__bf16*)alloc(262144 * 2);
  __bf16* Wga_h = (__bf16*)alloc(262144 * 2);
  __bf16* Wga_l = (__bf16*)alloc(262144 * 2);
  __bf16* Wgb_h = (__bf16*)alloc(262144 * 2);
  __bf16* Wgb_l = (__bf16*)alloc(262144 * 2);
  __bf16* Wgc_h = (__bf16*)alloc(262144 * 2);
  __bf16* Wgc_l = (__bf16*)alloc(262144 * 2);
  __bf16* Wes_h = (__bf16*)alloc(262144 * 2);
  __bf16* Wes_l = (__bf16*)alloc(262144 * 2);

  float* x3out  = (float*)d_out;             // output 0
  float* relout = (float*)d_out + 131072;    // output 1

  Prep pp;
  pp.w[0] = {W_go, Wgo_h, Wgo_l};
  pp.w[1] = {Wrel_top, Wrt_h, Wrt_l};
  pp.w[2] = {Wrel_bot, Wrb_h, Wrb_l};
  pp.w[3] = {Wgr_a, Wga_h, Wga_l};
  pp.w[4] = {Wgr_b, Wgb_h, Wgb_l};
  pp.w[5] = {Wgr_c, Wgc_h, Wgc_l};
  pp.w[6] = {W_esa, Wes_h, Wes_l};
  pp.x0 = x0; pp.x0h = x0h; pp.x0l = x0l;
  pp.b_rel = b_rel; pp.Wgrc = Wgr_c; pp.b_gr = b_gr; pp.dvec = dvec;
  prep_kernel<<<dim3(256, 9), 256, 0, stream>>>(pp);

  MBatch m1 = {};
  m1.op[0] = {x0h, x0l, Wgo_h, Wgo_l, b_go, nullptr, nullptr, x1h, x1l, 1};
  m1.op[1] = {x0h, x0l, Wrt_h, Wrt_l, nullptr, nullptr, nullptr, u0h, u0l, 0};
  m1.op[2] = {x0h, x0l, Wrb_h, Wrb_l, nullptr, nullptr, nullptr, v0h, v0l, 0};
  m1.op[3] = {x0h, x0l, Wga_h, Wga_l, nullptr, nullptr, p0t, nullptr, nullptr, 0};
  m1.op[4] = {x0h, x0l, Wgb_h, Wgb_l, nullptr, nullptr, q0t, nullptr, nullptr, 0};
  mfma_small_kernel<<<dim3(32, 5), 256, 0, stream>>>(m1);

  MBatch m2 = {};
  m2.op[0] = {x1h, x1l, Wgo_h, Wgo_l, b_go, nullptr, nullptr, x2h, x2l, 1};
  m2.op[1] = {u0h, u0l, Wgc_h, Wgc_l, dvec, p0t, Abuf, nullptr, nullptr, 0};
  m2.op[2] = {v0h, v0l, Wgc_h, Wgc_l, nullptr, q0t, Cbuf, nullptr, nullptr, 0};
  m2.op[3] = {x1h, x1l, Wga_h, Wga_l, b_gr, nullptr, p1, nullptr, nullptr, 0};
  m2.op[4] = {x1h, x1l, Wgb_h, Wgb_l, nullptr, nullptr, q1, nullptr, nullptr, 0};
  mfma_small_kernel<<<dim3(32, 5), 256, 0, stream>>>(m2);

  // m3 batch + rel1 fold: y=0..2 GEMM ops (x<32), y=3 rel1 (256 blocks)
  MBatch m3 = {};
  m3.op[0] = {x2h, x2l, Wgo_h, Wgo_l, b_go, nullptr, x3out, nullptr, nullptr, 1};
  m3.op[1] = {x2h, x2l, Wga_h, Wga_l, b_gr, nullptr, p2, nullptr, nullptr, 0};
  m3.op[2] = {x2h, x2l, Wgb_h, Wgb_l, nullptr, nullptr, q2, nullptr, nullptr, 0};
  m3_rel1_kernel<<<dim3(256, 4), 256, 0, stream>>>(m3, Abuf, Cbuf, R1);

  // rel2 = tanh(rel1@Wgr_c + p1[i] + q1[j])
  big_gemm_kernel<1><<<1024, 256, 0, stream>>>(R1, Wgc_h, p1, q1, nullptr, R2, nullptr);
  // rel3 = tanh(rel2@Wgr_c + p2[i] + q2[j])
  big_gemm_kernel<1><<<1024, 256, 0, stream>>>(R2, Wgc_h, p2, q2, nullptr, R1, nullptr);
  // S = rel3@W_esa + b_esa
  big_gemm_kernel<2><<<1024, 256, 0, stream>>>(R1, Wes_h, nullptr, nullptr, b_esa, nullptr, S);

  softmax_l_kernel<<<512, 256, 0, stream>>>(S, Lb);
  softmax_out_kernel<<<512, 256, 0, stream>>>(S, Lb, relout);
}